// Round 1
// baseline (411.732 us; speedup 1.0000x reference)
//
#include <hip/hip_runtime.h>
#include <math.h>

#define NODES 100000
#define EDGES 1600000
#define HF 128
#define NC 20
#define BSHIFT 9
#define BK 512                          // nodes per bucket
#define NBK ((NODES + BK - 1) / BK)     // 196 buckets
#define CAP 8704                        // bucket capacity (mean 8192, max ~8500)
#define EPB 8192                        // edges per partition block
#define NPB ((EDGES + EPB - 1) / EPB)   // 196 blocks
#define EIDX_CAP 2048                   // per-64-node edge window (mean 1024, sd 32)

typedef __attribute__((ext_vector_type(8))) short bf16x8;
typedef __attribute__((ext_vector_type(4))) float f32x4;
typedef __attribute__((ext_vector_type(2))) float f32x2;

__device__ __forceinline__ ushort f2b(float f) {
    uint u = __float_as_uint(f);
    uint r = (u + 0x7FFFu + ((u >> 16) & 1u)) >> 16;
    return (ushort)r;
}
__device__ __forceinline__ uchar f2q(float f) {
    return (uchar)(__builtin_amdgcn_cvt_pk_fp8_f32(f, f, 0, false) & 0xFF);
}

// ---- merged converters + edge partition (one dispatch; bcur pre-zeroed) ----
#define XB ((NODES * HF / 8 + 255) / 256)

__global__ void prep_kernel(const float* __restrict__ x, ushort* __restrict__ xb,
                            uchar* __restrict__ xq,
                            const float* __restrict__ a, const float* __restrict__ b,
                            const float* __restrict__ c, const float* __restrict__ d,
                            const float* __restrict__ e, const float* __restrict__ wm2,
                            ushort* __restrict__ wb,
                            const int* __restrict__ src, const int* __restrict__ dst,
                            int* __restrict__ bcur, uint2* __restrict__ ebuf,
                            int n8, int E) {
    __shared__ int h[NBK];
    __shared__ int basea[NBK];
    int blk = blockIdx.x;
    int t = threadIdx.x;
    if (blk < XB) {
        // ---- x -> bf16 + fp8 ----
        int i = blk * 256 + t;
        if (i >= n8) return;
        const float4* p = (const float4*)x + (size_t)i * 2;
        float4 va = p[0], vb = p[1];
        uint4 o;
        o.x = (uint)f2b(va.x) | ((uint)f2b(va.y) << 16);
        o.y = (uint)f2b(va.z) | ((uint)f2b(va.w) << 16);
        o.z = (uint)f2b(vb.x) | ((uint)f2b(vb.y) << 16);
        o.w = (uint)f2b(vb.z) | ((uint)f2b(vb.w) << 16);
        ((uint4*)xb)[i] = o;
        uint2 q;
        q.x = __builtin_amdgcn_cvt_pk_fp8_f32(va.x, va.y, 0, false);
        q.x = __builtin_amdgcn_cvt_pk_fp8_f32(va.z, va.w, q.x, true);
        q.y = __builtin_amdgcn_cvt_pk_fp8_f32(vb.x, vb.y, 0, false);
        q.y = __builtin_amdgcn_cvt_pk_fp8_f32(vb.z, vb.w, q.y, true);
        ((uint2*)xq)[i] = q;
    } else if (blk < XB + 336) {
        // ---- weights -> bf16 ----
        int i = (blk - XB) * 256 + t;
        if (i < 81920) {
            const float* srcs[5] = {a, b, c, d, e};
            wb[i] = f2b(srcs[i >> 14][i & 16383]);
        } else if (i < 86016) {
            int j = i - 81920;
            wb[i] = ((j >> 7) < NC) ? f2b(wm2[j]) : (ushort)0;
        }
    } else {
        // ---- fixed-capacity bucketed partition of edges by dst ----
        // bcur holds RELATIVE counts (zero-initialized by hipMemsetAsync);
        // absolute base = bucket*CAP + relative offset.
        int base = (blk - XB - 336) * EPB;
        for (int i = t; i < NBK; i += 256) h[i] = 0;
        __syncthreads();
        for (int i = t; i < EPB; i += 256) {
            int ee = base + i;
            if (ee < E) atomicAdd(&h[dst[ee] >> BSHIFT], 1);
        }
        __syncthreads();
        for (int i = t; i < NBK; i += 256) {
            int cc = h[i];
            basea[i] = cc ? (i * CAP + atomicAdd(&bcur[i], cc)) : 0;
        }
        __syncthreads();
        for (int i = t; i < NBK; i += 256) h[i] = 0;
        __syncthreads();
        for (int i = t; i < EPB; i += 256) {
            int ee = base + i;
            if (ee < E) {
                int dd = dst[ee];
                int bb = dd >> BSHIFT;
                int pos = basea[bb] + atomicAdd(&h[bb], 1);
                ebuf[pos] = make_uint2((uint)src[ee], (uint)dd);
            }
        }
    }
}

__global__ void bucket_sort(const uint2* __restrict__ ebuf, const int* __restrict__ bcur,
                            int* __restrict__ soff, int* __restrict__ eoff,
                            int* __restrict__ ssrc, int n) {
    __shared__ int deg[BK];
    __shared__ int lcur[BK];
    __shared__ int ps[BK];
    int b = blockIdx.x;
    int t = threadIdx.x;  // 0..511
    int e0 = b * CAP, e1 = b * CAP + bcur[b];   // bcur is relative count now
    int nbase = b << BSHIFT;

    deg[t] = 0;
    __syncthreads();
    for (int e = e0 + t; e < e1; e += BK)
        atomicAdd(&deg[ebuf[e].y & (BK - 1)], 1);
    __syncthreads();
    ps[t] = deg[t];
    __syncthreads();
    for (int st = 1; st < BK; st <<= 1) {
        int u = (t >= st) ? ps[t - st] : 0;
        __syncthreads();
        ps[t] += u;
        __syncthreads();
    }
    int start = e0 + ((t == 0) ? 0 : ps[t - 1]);
    lcur[t] = start;
    int node = nbase + t;
    if (node < n) { soff[node] = start; eoff[node] = start + deg[t]; }
    __syncthreads();
    for (int e = e0 + t; e < e1; e += BK) {
        uint2 ed = ebuf[e];
        int pos = atomicAdd(&lcur[ed.y & (BK - 1)], 1);
        ssrc[pos] = (int)ed.x;
    }
}

// ---- fused SAGE layer: out = relu(bias + mean_agg(Xq)@Wl^T + X@Wr^T) ----
// Phase 0: stage soff/eoff (64 nodes) + the block's contiguous edge-index
//   window (~1024 ints) into LDS.
// Phase 1: fp8 row gather: 32 lanes/node = 4-way edge interleave x 8 col-groups.
//   ALL rounds run at full 4-load depth with exec-masked validity (fp8 zero
//   contributes 0.0 -> identical math); no serial 1-load tail. LDS index path
//   is specialized so idx reads compile to ds_read (not flat).
// Phase 2: 8 waves MFMA dual linear; NT hints keep the streaming root rows and
//   output stores from evicting the hot Xq gather set out of L2.
template<bool EMITQ>
__global__ __launch_bounds__(512)
void fused_sage_layer(const uchar* __restrict__ Xq, const ushort* __restrict__ X,
                      const int* __restrict__ ssrc, const int* __restrict__ soff,
                      const int* __restrict__ eoff,
                      const ushort* __restrict__ Wl, const ushort* __restrict__ Wr,
                      const float* __restrict__ bias, ushort* __restrict__ out,
                      uchar* __restrict__ outq, int n) {
    __shared__ ushort sh[64][136];   // 17408 B
    __shared__ int sidx[EIDX_CAP];   // 8192 B
    __shared__ int s_se[128];        // soff[0..63] / eoff[64..127]
    int row0b = blockIdx.x * 64;
    int t = threadIdx.x;

    // ---- phase 0: stage offsets + edge-index window ----
    int last = min(row0b + 63, n - 1);
    int lo = soff[row0b];
    int hi = eoff[last];
    if (t < 64) {
        int node = row0b + t;
        s_se[t]      = (node < n) ? soff[node] : lo;
        s_se[64 + t] = (node < n) ? eoff[node] : lo;
    }
    bool useLds = (hi - lo) <= EIDX_CAP;   // block-uniform; ~always true
    int staged = useLds ? (hi - lo) : 0;
    for (int i = t; i < staged; i += 512) sidx[i] = ssrc[lo + i];
    __syncthreads();

    // ---- phase 1: fp8 gather ----
    {
        int sub = t & 31;
        int sel = sub >> 3;            // 0..3: edge interleave
        int cg = sub & 7;              // col-group: 16 fp8 cols = 16 B
        const uchar* xc = Xq + cg * 16;
        for (int batch = 0; batch < 4; ++batch) {
            int nloc = batch * 16 + (t >> 5);
            int node = row0b + nloc;
            float acc[16];
#pragma unroll
            for (int i = 0; i < 16; ++i) acc[i] = 0.f;
            int s0 = s_se[nloc], s1 = s_se[64 + nloc];
            int len = (node < n) ? (s1 - s0) : 0;
            int base = s0 - lo;

            auto body = [&](auto idxat) {
                for (int e = 0; e < len; e += 16) {
                    uint4 v[4];
#pragma unroll
                    for (int w = 0; w < 4; ++w) {
                        int ee = e + 4 * w + sel;
                        int idx = idxat(ee);          // clamped, always in-bounds
                        uint4 vv = {0u, 0u, 0u, 0u};
                        if (ee < len)
                            vv = *(const uint4*)(xc + (size_t)idx * HF);
                        v[w] = vv;                    // fp8 0x00 -> 0.0f: adds 0
                    }
#pragma unroll
                    for (int w = 0; w < 4; ++w) {
                        const uint* pp = (const uint*)&v[w];
#pragma unroll
                        for (int i = 0; i < 4; ++i) {
                            f32x2 lof = __builtin_amdgcn_cvt_pk_f32_fp8(pp[i], false);
                            f32x2 hif = __builtin_amdgcn_cvt_pk_f32_fp8(pp[i], true);
                            acc[4 * i]     += lof.x;
                            acc[4 * i + 1] += lof.y;
                            acc[4 * i + 2] += hif.x;
                            acc[4 * i + 3] += hif.y;
                        }
                    }
                }
            };
            if (useLds) {
                // direct __shared__ indexing -> ds_read_b32 (broadcast across cg)
                body([&](int ee) { return sidx[min(base + ee, EIDX_CAP - 1)]; });
            } else {
                const int* gep = ssrc + s0;
                body([&](int ee) { return gep[min(ee, len - 1)]; });
            }
#pragma unroll
            for (int i = 0; i < 16; ++i) {
                acc[i] += __shfl_xor(acc[i], 8);
                acc[i] += __shfl_xor(acc[i], 16);
            }
            if (sel == 0 && node < n) {
                float invd = 1.0f / fmaxf((float)len, 1.0f);
                uint4 o0, o1;
                uint* p0 = (uint*)&o0;
                uint* p1 = (uint*)&o1;
#pragma unroll
                for (int i = 0; i < 4; ++i) {
                    p0[i] = (uint)f2b(acc[2 * i] * invd) | ((uint)f2b(acc[2 * i + 1] * invd) << 16);
                    p1[i] = (uint)f2b(acc[8 + 2 * i] * invd) | ((uint)f2b(acc[8 + 2 * i + 1] * invd) << 16);
                }
                *(uint4*)(&sh[nloc][cg * 16]) = o0;
                *(uint4*)(&sh[nloc][cg * 16 + 8]) = o1;
            }
        }
    }
    __syncthreads();

    // ---- phase 2: dual MFMA linear ----
    int wave = t >> 6;           // 0..7 -> col tile
    int lane = t & 63;
    int m = lane & 15, quad = lane >> 4;
    int col = wave * 16 + m;

    bf16x8 bl[4], br[4];
#pragma unroll
    for (int ks = 0; ks < 4; ++ks) {
        bl[ks] = *(const bf16x8*)(Wl + (size_t)col * HF + ks * 32 + quad * 8);
        br[ks] = *(const bf16x8*)(Wr + (size_t)col * HF + ks * 32 + quad * 8);
    }
    float bia = bias[col];

#pragma unroll
    for (int rt = 0; rt < 4; ++rt) {
        int row0 = row0b + rt * 16;
        if (row0 >= n) break;
        f32x4 acc = {0.f, 0.f, 0.f, 0.f};
        const ushort* arow = X + (size_t)(row0 + m) * HF + quad * 8;  // root row
#pragma unroll
        for (int ks = 0; ks < 4; ++ks) {
            bf16x8 a = *(const bf16x8*)(&sh[rt * 16 + m][ks * 32 + quad * 8]);
            acc = __builtin_amdgcn_mfma_f32_16x16x32_bf16(a, bl[ks], acc, 0, 0, 0);
            bf16x8 ar = __builtin_nontemporal_load((const bf16x8*)(arow + ks * 32));
            acc = __builtin_amdgcn_mfma_f32_16x16x32_bf16(ar, br[ks], acc, 0, 0, 0);
        }
        // C/D layout: col = lane&15, row = quad*4 + reg
#pragma unroll
        for (int i = 0; i < 4; ++i) {
            int r = row0 + quad * 4 + i;
            if (r < n) {
                float v = fmaxf(acc[i] + bia, 0.f);
                __builtin_nontemporal_store(f2b(v), &out[(size_t)r * HF + col]);
                if (EMITQ)
                    __builtin_nontemporal_store(f2q(v), &outq[(size_t)r * HF + col]);
            }
        }
    }
}

// ---- fused MLP hidden + head: out = sigmoid(relu(A@Wm1^T+bm1) @ Wm2^T + bm2) ----
__global__ __launch_bounds__(256)
void mfma_mlp_head(const ushort* __restrict__ A, const ushort* __restrict__ Wm1b,
                   const ushort* __restrict__ Wm2b, const float* __restrict__ bm1,
                   const float* __restrict__ bm2, float* __restrict__ out, int n) {
    __shared__ ushort sh3[64][136];
    int wave = threadIdx.x >> 6;
    int lane = threadIdx.x & 63;
    int m = lane & 15, quad = lane >> 4;
    int row0b = blockIdx.x * 64;

    bf16x8 b1[2][4];
#pragma unroll
    for (int ct = 0; ct < 2; ++ct) {
        int col = wave * 32 + ct * 16 + m;
#pragma unroll
        for (int ks = 0; ks < 4; ++ks)
            b1[ct][ks] = *(const bf16x8*)(Wm1b + (size_t)col * HF + ks * 32 + quad * 8);
    }
    float bia0 = bm1[wave * 32 + m];
    float bia1 = bm1[wave * 32 + 16 + m];

#pragma unroll
    for (int rt = 0; rt < 4; ++rt) {
        int row0 = row0b + rt * 16;
        if (row0 >= n) break;
        f32x4 acc0 = {0.f, 0.f, 0.f, 0.f};
        f32x4 acc1 = {0.f, 0.f, 0.f, 0.f};
        const ushort* arow = A + (size_t)(row0 + m) * HF + quad * 8;
#pragma unroll
        for (int ks = 0; ks < 4; ++ks) {
            bf16x8 a = *(const bf16x8*)(arow + ks * 32);
            acc0 = __builtin_amdgcn_mfma_f32_16x16x32_bf16(a, b1[0][ks], acc0, 0, 0, 0);
            acc1 = __builtin_amdgcn_mfma_f32_16x16x32_bf16(a, b1[1][ks], acc1, 0, 0, 0);
        }
#pragma unroll
        for (int i = 0; i < 4; ++i) {
            int rl = rt * 16 + quad * 4 + i;
            sh3[rl][wave * 32 + m]      = f2b(fmaxf(acc0[i] + bia0, 0.f));
            sh3[rl][wave * 32 + 16 + m] = f2b(fmaxf(acc1[i] + bia1, 0.f));
        }
    }
    __syncthreads();

    bf16x8 c0f[4], c1f[4];
#pragma unroll
    for (int ks = 0; ks < 4; ++ks) {
        c0f[ks] = *(const bf16x8*)(Wm2b + (size_t)m * HF + ks * 32 + quad * 8);
        c1f[ks] = *(const bf16x8*)(Wm2b + (size_t)(16 + m) * HF + ks * 32 + quad * 8);
    }
    f32x4 o0 = {0.f, 0.f, 0.f, 0.f};
    f32x4 o1 = {0.f, 0.f, 0.f, 0.f};
#pragma unroll
    for (int ks = 0; ks < 4; ++ks) {
        bf16x8 a = *(const bf16x8*)(&sh3[wave * 16 + m][ks * 32 + quad * 8]);
        o0 = __builtin_amdgcn_mfma_f32_16x16x32_bf16(a, c0f[ks], o0, 0, 0, 0);
        o1 = __builtin_amdgcn_mfma_f32_16x16x32_bf16(a, c1f[ks], o1, 0, 0, 0);
    }
    float bb0 = bm2[m];
    float bb1 = (m < 4) ? bm2[16 + m] : 0.f;
#pragma unroll
    for (int i = 0; i < 4; ++i) {
        int row = row0b + wave * 16 + quad * 4 + i;
        if (row < n) {
            out[(size_t)row * NC + m] = 1.0f / (1.0f + expf(-(o0[i] + bb0)));
            if (m < 4)
                out[(size_t)row * NC + 16 + m] = 1.0f / (1.0f + expf(-(o1[i] + bb1)));
        }
    }
}

extern "C" void kernel_launch(void* const* d_in, const int* in_sizes, int n_in,
                              void* d_out, int out_size, void* d_ws, size_t ws_size,
                              hipStream_t stream) {
    const float* x   = (const float*)d_in[0];
    const int*   ei  = (const int*)d_in[1];
    const float* W1l = (const float*)d_in[2];
    const float* b1  = (const float*)d_in[3];
    const float* W1r = (const float*)d_in[4];
    const float* W2l = (const float*)d_in[5];
    const float* b2  = (const float*)d_in[6];
    const float* W2r = (const float*)d_in[7];
    const float* Wm1 = (const float*)d_in[8];
    const float* bm1 = (const float*)d_in[9];
    const float* Wm2 = (const float*)d_in[10];
    const float* bm2 = (const float*)d_in[11];
    float* out = (float*)d_out;

    const int N = NODES, E = EDGES;
    const int* src = ei;
    const int* dst = ei + E;

    // workspace layout (16B-aligned sections)
    int* bcur   = (int*)d_ws;            // 256
    int* soff   = bcur + 256;            // N+8
    int* eoff   = soff + N + 8;          // N+8
    int* ssrc   = eoff + N + 8;          // NBK*CAP
    ushort* xb   = (ushort*)(ssrc + NBK * CAP);  // N*HF bf16
    ushort* h1   = xb + (size_t)N * HF;          // N*HF bf16
    ushort* h2   = h1 + (size_t)N * HF;          // N*HF bf16
    uint2* ebuf  = (uint2*)h2;                   // aliases h2 (dead after bucket_sort)
    ushort* wb   = h2 + (size_t)N * HF;          // 86016 bf16 weights
    uchar* xq    = (uchar*)(wb + 86016);         // N*HF fp8
    uchar* h1q   = xq + (size_t)N * HF;          // N*HF fp8
    ushort* wb1l = wb;
    ushort* wb1r = wb + 16384;
    ushort* wb2l = wb + 32768;
    ushort* wb2r = wb + 49152;
    ushort* wbm1 = wb + 65536;
    ushort* wbm2 = wb + 81920;

    const int n8 = N * HF / 8;

    // ---- zero relative bucket counters, then merged converters + partition ----
    hipMemsetAsync(bcur, 0, NBK * sizeof(int), stream);
    prep_kernel<<<XB + 336 + NPB, 256, 0, stream>>>(
        x, xb, xq, W1l, W1r, W2l, W2r, Wm1, Wm2, wb, src, dst, bcur, ebuf, n8, E);
    bucket_sort<<<NBK, BK, 0, stream>>>(ebuf, bcur, soff, eoff, ssrc, N);

    const int fusedBlocks = (N + 63) / 64;

    // ---- layer 1: fp8 gather + dual linear, emits h1 (bf16) + h1q (fp8) ----
    fused_sage_layer<true><<<fusedBlocks, 512, 0, stream>>>(
        xq, xb, ssrc, soff, eoff, wb1l, wb1r, b1, h1, h1q, N);
    // ---- layer 2 ----
    fused_sage_layer<false><<<fusedBlocks, 512, 0, stream>>>(
        h1q, h1, ssrc, soff, eoff, wb2l, wb2r, b2, h2, nullptr, N);
    // ---- fused MLP hidden + head + sigmoid ----
    mfma_mlp_head<<<fusedBlocks, 256, 0, stream>>>(h2, wbm1, wbm2, bm1, bm2, out, N);
}

// Round 2
// 359.713 us; speedup vs baseline: 1.1446x; 1.1446x over previous
//
#include <hip/hip_runtime.h>
#include <math.h>

#define NODES 100000
#define EDGES 1600000
#define HF 128
#define NC 20
#define BSHIFT 9
#define BK 512                          // nodes per bucket
#define NBK ((NODES + BK - 1) / BK)     // 196 buckets
#define CAP 8704                        // bucket capacity (mean 8192, max ~8500)
#define EPB 8192                        // edges per partition block
#define NPB ((EDGES + EPB - 1) / EPB)   // 196 blocks
#define EIDX_CAP 2048                   // per-64-node edge window (mean 1024, sd 32)

typedef __attribute__((ext_vector_type(8))) short bf16x8;
typedef __attribute__((ext_vector_type(4))) float f32x4;
typedef __attribute__((ext_vector_type(2))) float f32x2;

__device__ __forceinline__ ushort f2b(float f) {
    uint u = __float_as_uint(f);
    uint r = (u + 0x7FFFu + ((u >> 16) & 1u)) >> 16;
    return (ushort)r;
}
__device__ __forceinline__ uchar f2q(float f) {
    return (uchar)(__builtin_amdgcn_cvt_pk_fp8_f32(f, f, 0, false) & 0xFF);
}

// ---- merged converters + edge partition (one dispatch; bcur pre-zeroed) ----
#define XB ((NODES * HF / 8 + 255) / 256)

__global__ void prep_kernel(const float* __restrict__ x, ushort* __restrict__ xb,
                            uchar* __restrict__ xq,
                            const float* __restrict__ a, const float* __restrict__ b,
                            const float* __restrict__ c, const float* __restrict__ d,
                            const float* __restrict__ e, const float* __restrict__ wm2,
                            ushort* __restrict__ wb,
                            const int* __restrict__ src, const int* __restrict__ dst,
                            int* __restrict__ bcur, uint2* __restrict__ ebuf,
                            int n8, int E) {
    __shared__ int h[NBK];
    __shared__ int basea[NBK];
    int blk = blockIdx.x;
    int t = threadIdx.x;
    if (blk < XB) {
        // ---- x -> bf16 + fp8 ----
        int i = blk * 256 + t;
        if (i >= n8) return;
        const float4* p = (const float4*)x + (size_t)i * 2;
        float4 va = p[0], vb = p[1];
        uint4 o;
        o.x = (uint)f2b(va.x) | ((uint)f2b(va.y) << 16);
        o.y = (uint)f2b(va.z) | ((uint)f2b(va.w) << 16);
        o.z = (uint)f2b(vb.x) | ((uint)f2b(vb.y) << 16);
        o.w = (uint)f2b(vb.z) | ((uint)f2b(vb.w) << 16);
        ((uint4*)xb)[i] = o;
        uint2 q;
        q.x = __builtin_amdgcn_cvt_pk_fp8_f32(va.x, va.y, 0, false);
        q.x = __builtin_amdgcn_cvt_pk_fp8_f32(va.z, va.w, q.x, true);
        q.y = __builtin_amdgcn_cvt_pk_fp8_f32(vb.x, vb.y, 0, false);
        q.y = __builtin_amdgcn_cvt_pk_fp8_f32(vb.z, vb.w, q.y, true);
        ((uint2*)xq)[i] = q;
    } else if (blk < XB + 336) {
        // ---- weights -> bf16 ----
        int i = (blk - XB) * 256 + t;
        if (i < 81920) {
            const float* srcs[5] = {a, b, c, d, e};
            wb[i] = f2b(srcs[i >> 14][i & 16383]);
        } else if (i < 86016) {
            int j = i - 81920;
            wb[i] = ((j >> 7) < NC) ? f2b(wm2[j]) : (ushort)0;
        }
    } else {
        // ---- fixed-capacity bucketed partition of edges by dst ----
        // bcur holds RELATIVE counts (zero-initialized by hipMemsetAsync);
        // absolute base = bucket*CAP + relative offset.
        int base = (blk - XB - 336) * EPB;
        for (int i = t; i < NBK; i += 256) h[i] = 0;
        __syncthreads();
        for (int i = t; i < EPB; i += 256) {
            int ee = base + i;
            if (ee < E) atomicAdd(&h[dst[ee] >> BSHIFT], 1);
        }
        __syncthreads();
        for (int i = t; i < NBK; i += 256) {
            int cc = h[i];
            basea[i] = cc ? (i * CAP + atomicAdd(&bcur[i], cc)) : 0;
        }
        __syncthreads();
        for (int i = t; i < NBK; i += 256) h[i] = 0;
        __syncthreads();
        for (int i = t; i < EPB; i += 256) {
            int ee = base + i;
            if (ee < E) {
                int dd = dst[ee];
                int bb = dd >> BSHIFT;
                int pos = basea[bb] + atomicAdd(&h[bb], 1);
                ebuf[pos] = make_uint2((uint)src[ee], (uint)dd);
            }
        }
    }
}

__global__ void bucket_sort(const uint2* __restrict__ ebuf, const int* __restrict__ bcur,
                            int* __restrict__ soff, int* __restrict__ eoff,
                            int* __restrict__ ssrc, int n) {
    __shared__ int deg[BK];
    __shared__ int lcur[BK];
    __shared__ int ps[BK];
    int b = blockIdx.x;
    int t = threadIdx.x;  // 0..511
    int e0 = b * CAP, e1 = b * CAP + bcur[b];   // bcur is relative count
    int nbase = b << BSHIFT;

    deg[t] = 0;
    __syncthreads();
    for (int e = e0 + t; e < e1; e += BK)
        atomicAdd(&deg[ebuf[e].y & (BK - 1)], 1);
    __syncthreads();
    ps[t] = deg[t];
    __syncthreads();
    for (int st = 1; st < BK; st <<= 1) {
        int u = (t >= st) ? ps[t - st] : 0;
        __syncthreads();
        ps[t] += u;
        __syncthreads();
    }
    int start = e0 + ((t == 0) ? 0 : ps[t - 1]);
    lcur[t] = start;
    int node = nbase + t;
    if (node < n) { soff[node] = start; eoff[node] = start + deg[t]; }
    __syncthreads();
    for (int e = e0 + t; e < e1; e += BK) {
        uint2 ed = ebuf[e];
        int pos = atomicAdd(&lcur[ed.y & (BK - 1)], 1);
        ssrc[pos] = (int)ed.x;
    }
}

// ---- fused SAGE layer: out = relu(bias + mean_agg(Xq)@Wl^T + X@Wr^T) ----
// Phase 0: stage soff/eoff (64 nodes) + the block's contiguous edge-index
//   window (~1024 ints) into LDS.
// Phase 1: fp8 row gather: 32 lanes/node = 4-way edge interleave x 8 col-groups.
//   ALL rounds run at full 4-load depth with exec-masked validity (fp8 zero
//   contributes 0.0 -> identical math); no serial 1-load tail. LDS index path
//   is specialized so idx reads compile to ds_read (not flat).
// Phase 2: 8 waves MFMA dual linear. Plain (cached) loads/stores — NT hints
//   measured: +44MB WRITE (partial-line writeback) +22MB FETCH (L2 evict of
//   h1/h1q before layer-2 reuse) = net regression. Keep L2-cooperative.
template<bool EMITQ>
__global__ __launch_bounds__(512)
void fused_sage_layer(const uchar* __restrict__ Xq, const ushort* __restrict__ X,
                      const int* __restrict__ ssrc, const int* __restrict__ soff,
                      const int* __restrict__ eoff,
                      const ushort* __restrict__ Wl, const ushort* __restrict__ Wr,
                      const float* __restrict__ bias, ushort* __restrict__ out,
                      uchar* __restrict__ outq, int n) {
    __shared__ ushort sh[64][136];   // 17408 B
    __shared__ int sidx[EIDX_CAP];   // 8192 B
    __shared__ int s_se[128];        // soff[0..63] / eoff[64..127]
    int row0b = blockIdx.x * 64;
    int t = threadIdx.x;

    // ---- phase 0: stage offsets + edge-index window ----
    int last = min(row0b + 63, n - 1);
    int lo = soff[row0b];
    int hi = eoff[last];
    if (t < 64) {
        int node = row0b + t;
        s_se[t]      = (node < n) ? soff[node] : lo;
        s_se[64 + t] = (node < n) ? eoff[node] : lo;
    }
    bool useLds = (hi - lo) <= EIDX_CAP;   // block-uniform; ~always true
    int staged = useLds ? (hi - lo) : 0;
    for (int i = t; i < staged; i += 512) sidx[i] = ssrc[lo + i];
    __syncthreads();

    // ---- phase 1: fp8 gather ----
    {
        int sub = t & 31;
        int sel = sub >> 3;            // 0..3: edge interleave
        int cg = sub & 7;              // col-group: 16 fp8 cols = 16 B
        const uchar* xc = Xq + cg * 16;
        for (int batch = 0; batch < 4; ++batch) {
            int nloc = batch * 16 + (t >> 5);
            int node = row0b + nloc;
            float acc[16];
#pragma unroll
            for (int i = 0; i < 16; ++i) acc[i] = 0.f;
            int s0 = s_se[nloc], s1 = s_se[64 + nloc];
            int len = (node < n) ? (s1 - s0) : 0;
            int base = s0 - lo;

            auto body = [&](auto idxat) {
                for (int e = 0; e < len; e += 16) {
                    uint4 v[4];
#pragma unroll
                    for (int w = 0; w < 4; ++w) {
                        int ee = e + 4 * w + sel;
                        int idx = idxat(ee);          // clamped, always in-bounds
                        uint4 vv = {0u, 0u, 0u, 0u};
                        if (ee < len)
                            vv = *(const uint4*)(xc + (size_t)idx * HF);
                        v[w] = vv;                    // fp8 0x00 -> 0.0f: adds 0
                    }
#pragma unroll
                    for (int w = 0; w < 4; ++w) {
                        const uint* pp = (const uint*)&v[w];
#pragma unroll
                        for (int i = 0; i < 4; ++i) {
                            f32x2 lof = __builtin_amdgcn_cvt_pk_f32_fp8(pp[i], false);
                            f32x2 hif = __builtin_amdgcn_cvt_pk_f32_fp8(pp[i], true);
                            acc[4 * i]     += lof.x;
                            acc[4 * i + 1] += lof.y;
                            acc[4 * i + 2] += hif.x;
                            acc[4 * i + 3] += hif.y;
                        }
                    }
                }
            };
            if (useLds) {
                // direct __shared__ indexing -> ds_read_b32 (broadcast across cg)
                body([&](int ee) { return sidx[min(base + ee, EIDX_CAP - 1)]; });
            } else {
                const int* gep = ssrc + s0;
                body([&](int ee) { return gep[min(ee, len - 1)]; });
            }
#pragma unroll
            for (int i = 0; i < 16; ++i) {
                acc[i] += __shfl_xor(acc[i], 8);
                acc[i] += __shfl_xor(acc[i], 16);
            }
            if (sel == 0 && node < n) {
                float invd = 1.0f / fmaxf((float)len, 1.0f);
                uint4 o0, o1;
                uint* p0 = (uint*)&o0;
                uint* p1 = (uint*)&o1;
#pragma unroll
                for (int i = 0; i < 4; ++i) {
                    p0[i] = (uint)f2b(acc[2 * i] * invd) | ((uint)f2b(acc[2 * i + 1] * invd) << 16);
                    p1[i] = (uint)f2b(acc[8 + 2 * i] * invd) | ((uint)f2b(acc[8 + 2 * i + 1] * invd) << 16);
                }
                *(uint4*)(&sh[nloc][cg * 16]) = o0;
                *(uint4*)(&sh[nloc][cg * 16 + 8]) = o1;
            }
        }
    }
    __syncthreads();

    // ---- phase 2: dual MFMA linear ----
    int wave = t >> 6;           // 0..7 -> col tile
    int lane = t & 63;
    int m = lane & 15, quad = lane >> 4;
    int col = wave * 16 + m;

    bf16x8 bl[4], br[4];
#pragma unroll
    for (int ks = 0; ks < 4; ++ks) {
        bl[ks] = *(const bf16x8*)(Wl + (size_t)col * HF + ks * 32 + quad * 8);
        br[ks] = *(const bf16x8*)(Wr + (size_t)col * HF + ks * 32 + quad * 8);
    }
    float bia = bias[col];

#pragma unroll
    for (int rt = 0; rt < 4; ++rt) {
        int row0 = row0b + rt * 16;
        if (row0 >= n) break;
        f32x4 acc = {0.f, 0.f, 0.f, 0.f};
        const ushort* arow = X + (size_t)(row0 + m) * HF + quad * 8;  // root row
#pragma unroll
        for (int ks = 0; ks < 4; ++ks) {
            bf16x8 a = *(const bf16x8*)(&sh[rt * 16 + m][ks * 32 + quad * 8]);
            acc = __builtin_amdgcn_mfma_f32_16x16x32_bf16(a, bl[ks], acc, 0, 0, 0);
            bf16x8 ar = *(const bf16x8*)(arow + ks * 32);
            acc = __builtin_amdgcn_mfma_f32_16x16x32_bf16(ar, br[ks], acc, 0, 0, 0);
        }
        // C/D layout: col = lane&15, row = quad*4 + reg
#pragma unroll
        for (int i = 0; i < 4; ++i) {
            int r = row0 + quad * 4 + i;
            if (r < n) {
                float v = fmaxf(acc[i] + bia, 0.f);
                out[(size_t)r * HF + col] = f2b(v);
                if (EMITQ) outq[(size_t)r * HF + col] = f2q(v);
            }
        }
    }
}

// ---- fused MLP hidden + head: out = sigmoid(relu(A@Wm1^T+bm1) @ Wm2^T + bm2) ----
__global__ __launch_bounds__(256)
void mfma_mlp_head(const ushort* __restrict__ A, const ushort* __restrict__ Wm1b,
                   const ushort* __restrict__ Wm2b, const float* __restrict__ bm1,
                   const float* __restrict__ bm2, float* __restrict__ out, int n) {
    __shared__ ushort sh3[64][136];
    int wave = threadIdx.x >> 6;
    int lane = threadIdx.x & 63;
    int m = lane & 15, quad = lane >> 4;
    int row0b = blockIdx.x * 64;

    bf16x8 b1[2][4];
#pragma unroll
    for (int ct = 0; ct < 2; ++ct) {
        int col = wave * 32 + ct * 16 + m;
#pragma unroll
        for (int ks = 0; ks < 4; ++ks)
            b1[ct][ks] = *(const bf16x8*)(Wm1b + (size_t)col * HF + ks * 32 + quad * 8);
    }
    float bia0 = bm1[wave * 32 + m];
    float bia1 = bm1[wave * 32 + 16 + m];

#pragma unroll
    for (int rt = 0; rt < 4; ++rt) {
        int row0 = row0b + rt * 16;
        if (row0 >= n) break;
        f32x4 acc0 = {0.f, 0.f, 0.f, 0.f};
        f32x4 acc1 = {0.f, 0.f, 0.f, 0.f};
        const ushort* arow = A + (size_t)(row0 + m) * HF + quad * 8;
#pragma unroll
        for (int ks = 0; ks < 4; ++ks) {
            bf16x8 a = *(const bf16x8*)(arow + ks * 32);
            acc0 = __builtin_amdgcn_mfma_f32_16x16x32_bf16(a, b1[0][ks], acc0, 0, 0, 0);
            acc1 = __builtin_amdgcn_mfma_f32_16x16x32_bf16(a, b1[1][ks], acc1, 0, 0, 0);
        }
#pragma unroll
        for (int i = 0; i < 4; ++i) {
            int rl = rt * 16 + quad * 4 + i;
            sh3[rl][wave * 32 + m]      = f2b(fmaxf(acc0[i] + bia0, 0.f));
            sh3[rl][wave * 32 + 16 + m] = f2b(fmaxf(acc1[i] + bia1, 0.f));
        }
    }
    __syncthreads();

    bf16x8 c0f[4], c1f[4];
#pragma unroll
    for (int ks = 0; ks < 4; ++ks) {
        c0f[ks] = *(const bf16x8*)(Wm2b + (size_t)m * HF + ks * 32 + quad * 8);
        c1f[ks] = *(const bf16x8*)(Wm2b + (size_t)(16 + m) * HF + ks * 32 + quad * 8);
    }
    f32x4 o0 = {0.f, 0.f, 0.f, 0.f};
    f32x4 o1 = {0.f, 0.f, 0.f, 0.f};
#pragma unroll
    for (int ks = 0; ks < 4; ++ks) {
        bf16x8 a = *(const bf16x8*)(&sh3[wave * 16 + m][ks * 32 + quad * 8]);
        o0 = __builtin_amdgcn_mfma_f32_16x16x32_bf16(a, c0f[ks], o0, 0, 0, 0);
        o1 = __builtin_amdgcn_mfma_f32_16x16x32_bf16(a, c1f[ks], o1, 0, 0, 0);
    }
    float bb0 = bm2[m];
    float bb1 = (m < 4) ? bm2[16 + m] : 0.f;
#pragma unroll
    for (int i = 0; i < 4; ++i) {
        int row = row0b + wave * 16 + quad * 4 + i;
        if (row < n) {
            out[(size_t)row * NC + m] = 1.0f / (1.0f + expf(-(o0[i] + bb0)));
            if (m < 4)
                out[(size_t)row * NC + 16 + m] = 1.0f / (1.0f + expf(-(o1[i] + bb1)));
        }
    }
}

extern "C" void kernel_launch(void* const* d_in, const int* in_sizes, int n_in,
                              void* d_out, int out_size, void* d_ws, size_t ws_size,
                              hipStream_t stream) {
    const float* x   = (const float*)d_in[0];
    const int*   ei  = (const int*)d_in[1];
    const float* W1l = (const float*)d_in[2];
    const float* b1  = (const float*)d_in[3];
    const float* W1r = (const float*)d_in[4];
    const float* W2l = (const float*)d_in[5];
    const float* b2  = (const float*)d_in[6];
    const float* W2r = (const float*)d_in[7];
    const float* Wm1 = (const float*)d_in[8];
    const float* bm1 = (const float*)d_in[9];
    const float* Wm2 = (const float*)d_in[10];
    const float* bm2 = (const float*)d_in[11];
    float* out = (float*)d_out;

    const int N = NODES, E = EDGES;
    const int* src = ei;
    const int* dst = ei + E;

    // workspace layout (16B-aligned sections)
    int* bcur   = (int*)d_ws;            // 256
    int* soff   = bcur + 256;            // N+8
    int* eoff   = soff + N + 8;          // N+8
    int* ssrc   = eoff + N + 8;          // NBK*CAP
    ushort* xb   = (ushort*)(ssrc + NBK * CAP);  // N*HF bf16
    ushort* h1   = xb + (size_t)N * HF;          // N*HF bf16
    ushort* h2   = h1 + (size_t)N * HF;          // N*HF bf16
    uint2* ebuf  = (uint2*)h2;                   // aliases h2 (dead after bucket_sort)
    ushort* wb   = h2 + (size_t)N * HF;          // 86016 bf16 weights
    uchar* xq    = (uchar*)(wb + 86016);         // N*HF fp8
    uchar* h1q   = xq + (size_t)N * HF;          // N*HF fp8
    ushort* wb1l = wb;
    ushort* wb1r = wb + 16384;
    ushort* wb2l = wb + 32768;
    ushort* wb2r = wb + 49152;
    ushort* wbm1 = wb + 65536;
    ushort* wbm2 = wb + 81920;

    const int n8 = N * HF / 8;

    // ---- zero relative bucket counters, then merged converters + partition ----
    hipMemsetAsync(bcur, 0, NBK * sizeof(int), stream);
    prep_kernel<<<XB + 336 + NPB, 256, 0, stream>>>(
        x, xb, xq, W1l, W1r, W2l, W2r, Wm1, Wm2, wb, src, dst, bcur, ebuf, n8, E);
    bucket_sort<<<NBK, BK, 0, stream>>>(ebuf, bcur, soff, eoff, ssrc, N);

    const int fusedBlocks = (N + 63) / 64;

    // ---- layer 1: fp8 gather + dual linear, emits h1 (bf16) + h1q (fp8) ----
    fused_sage_layer<true><<<fusedBlocks, 512, 0, stream>>>(
        xq, xb, ssrc, soff, eoff, wb1l, wb1r, b1, h1, h1q, N);
    // ---- layer 2 ----
    fused_sage_layer<false><<<fusedBlocks, 512, 0, stream>>>(
        h1q, h1, ssrc, soff, eoff, wb2l, wb2r, b2, h2, nullptr, N);
    // ---- fused MLP hidden + head + sigmoid ----
    mfma_mlp_head<<<fusedBlocks, 256, 0, stream>>>(h2, wbm1, wbm2, bm1, bm2, out, N);
}